// Round 7
// baseline (6756.043 us; speedup 1.0000x reference)
//
#include <hip/hip_runtime.h>
#include <math.h>

// ---------------------------------------------------------------------------
// VAE_14482629722138 — round 7: round-6 persistent cooperative scheme with the
// decoder barrier-counter fix (cnts alloc 512B; decoder counter at cnts[64],
// zeroed — round 6 pointed it past the allocation into Wa weights, making the
// decoder barrier a no-op and corrupting two weights -> ts_rec race).
// B=512, T=64, CF=512, ZD=128, TDIM=520.
// ---------------------------------------------------------------------------

#define B 512
#define TT 64
#define CF 512
#define G4 2048
#define ZD 128
#define TDIM 520

typedef unsigned short u16;
typedef unsigned int u32;
typedef unsigned long long u64;
typedef short bf16x8 __attribute__((ext_vector_type(8)));
typedef float f32x4 __attribute__((ext_vector_type(4)));

__device__ __forceinline__ float sigm(float x) { return 1.f / (1.f + expf(-x)); }
__device__ __forceinline__ u16 f2bf(float f) {
    unsigned u = __float_as_uint(f);
    u += 0x7fffu + ((u >> 16) & 1u);
    return (u16)(u >> 16);
}
__device__ __forceinline__ float bf2f(u16 s) { return __uint_as_float(((unsigned)s) << 16); }
__device__ __forceinline__ u32 packbf(float v) {
    u16 h = f2bf(v);
    u16 l = f2bf(v - bf2f(h));
    return (u32)h | ((u32)l << 16);
}

// coherent (cross-XCD) access helpers: relaxed agent atomics -> sc1, no fences
__device__ __forceinline__ u64 cload64(const u32* p) {
    return __hip_atomic_load((const u64*)p, __ATOMIC_RELAXED, __HIP_MEMORY_SCOPE_AGENT);
}
__device__ __forceinline__ void cstore32(u32* p, u32 v) {
    __hip_atomic_store(p, v, __ATOMIC_RELAXED, __HIP_MEMORY_SCOPE_AGENT);
}
__device__ __forceinline__ float cloadf(const float* p) {
    return __hip_atomic_load(p, __ATOMIC_RELAXED, __HIP_MEMORY_SCOPE_AGENT);
}
__device__ __forceinline__ void cstoref(float* p, float v) {
    __hip_atomic_store(p, v, __ATOMIC_RELAXED, __HIP_MEMORY_SCOPE_AGENT);
}

// Monotonic grid barrier: no reset, no generation flips, no fences.
// __syncthreads() before the add drains each wave's vmem (compiler emits
// s_waitcnt vmcnt(0) before s_barrier), so all sc1 stores are at the
// coherence point before the count moves. Verified on HW by the round-6
// encoder (correct tcat through 63 barriers).
__device__ __forceinline__ void gbar(unsigned* cnt, unsigned& expected) {
    expected += 256u;
    __syncthreads();
    if (threadIdx.x == 0) {
        __builtin_amdgcn_s_waitcnt(0);
        asm volatile("" ::: "memory");
        __hip_atomic_fetch_add(cnt, 1u, __ATOMIC_RELAXED, __HIP_MEMORY_SCOPE_AGENT);
        long sp = 0;
        while (__hip_atomic_load(cnt, __ATOMIC_RELAXED, __HIP_MEMORY_SCOPE_AGENT) < expected) {
            __builtin_amdgcn_s_sleep(8);
            if (++sp > 100000000L) break;
        }
        asm volatile("" ::: "memory");
    }
    __syncthreads();
}

struct __align__(16) GemmShared {
    u16 A[2][2][64][40];   // [dbuf][hi/lo][row][k(+pad)]
    u16 Bw[2][2][64][40];
};

__device__ __forceinline__ void unpack8(u64 q0, u64 q1, u64 q2, u64 q3,
                                        uint4& vh, uint4& vl) {
    u32 w0 = (u32)q0, w1 = (u32)(q0 >> 32), w2 = (u32)q1, w3 = (u32)(q1 >> 32);
    u32 w4 = (u32)q2, w5 = (u32)(q2 >> 32), w6 = (u32)q3, w7 = (u32)(q3 >> 32);
    vh.x = (w0 & 0xffffu) | (w1 << 16); vh.y = (w2 & 0xffffu) | (w3 << 16);
    vh.z = (w4 & 0xffffu) | (w5 << 16); vh.w = (w6 & 0xffffu) | (w7 << 16);
    vl.x = (w0 >> 16) | (w1 & 0xffff0000u); vl.y = (w2 >> 16) | (w3 & 0xffff0000u);
    vl.z = (w4 >> 16) | (w5 & 0xffff0000u); vl.w = (w6 >> 16) | (w7 & 0xffff0000u);
}

// ---------------------------------------------------------------------------
// 64x64 MFMA tile over packed-u32 A (coherent loads) and u16 W (cached loads).
// TERMS=3: Ah*Bh + Ah*Bl + Al*Bh.  TERMS=2: Ah*Bh + Al*Bh (B hi only).
// acc[nt][r]: row = ws*16+quad*4+r, col = nt*16+fr.
// ---------------------------------------------------------------------------
template<int TERMS>
__device__ __forceinline__ void gemm64p(
    GemmShared& sh, const u32* __restrict__ Ap, int lda,
    const u16* __restrict__ Bh, const u16* __restrict__ Bl, int K,
    f32x4 acc[4])
{
    const int tid = threadIdx.x, lane = tid & 63, ws = tid >> 6;
    const int fr = lane & 15, quad = lane >> 4, ko = quad << 3;
    const int srr = tid >> 2, skq = (tid & 3) << 3;
    const u32* ap = Ap + srr * lda + skq;
    const u16* wph = Bh + srr * K + skq;
    const u16* wpl = (TERMS == 3) ? (Bl + srr * K + skq) : (const u16*)0;
    const int niter = K >> 5;
    {
        u64 q0 = cload64(ap), q1 = cload64(ap + 2), q2 = cload64(ap + 4), q3 = cload64(ap + 6);
        uint4 vh, vl; unpack8(q0, q1, q2, q3, vh, vl);
        *(uint4*)&sh.A[0][0][srr][skq] = vh;
        *(uint4*)&sh.A[0][1][srr][skq] = vl;
        *(uint4*)&sh.Bw[0][0][srr][skq] = *(const uint4*)wph;
        if (TERMS == 3) *(uint4*)&sh.Bw[0][1][srr][skq] = *(const uint4*)wpl;
    }
    __syncthreads();
    for (int i = 0; i < niter; ++i) {
        const int cur = i & 1, nxt = cur ^ 1;
        const bool pf = (i + 1 < niter);
        u64 q0, q1, q2, q3; uint4 pbh, pbl;
        if (pf) {
            int k = (i + 1) << 5;
            q0 = cload64(ap + k); q1 = cload64(ap + k + 2);
            q2 = cload64(ap + k + 4); q3 = cload64(ap + k + 6);
            pbh = *(const uint4*)(wph + k);
            if (TERMS == 3) pbl = *(const uint4*)(wpl + k);
        }
        bf16x8 ah = *(const bf16x8*)&sh.A[cur][0][(ws << 4) + fr][ko];
        bf16x8 al = *(const bf16x8*)&sh.A[cur][1][(ws << 4) + fr][ko];
        #pragma unroll
        for (int nt = 0; nt < 4; ++nt) {
            bf16x8 bh = *(const bf16x8*)&sh.Bw[cur][0][(nt << 4) + fr][ko];
            acc[nt] = __builtin_amdgcn_mfma_f32_16x16x32_bf16(ah, bh, acc[nt], 0, 0, 0);
            if (TERMS == 3) {
                bf16x8 bl = *(const bf16x8*)&sh.Bw[cur][1][(nt << 4) + fr][ko];
                acc[nt] = __builtin_amdgcn_mfma_f32_16x16x32_bf16(ah, bl, acc[nt], 0, 0, 0);
            }
            acc[nt] = __builtin_amdgcn_mfma_f32_16x16x32_bf16(al, bh, acc[nt], 0, 0, 0);
        }
        if (pf) {
            uint4 vh, vl; unpack8(q0, q1, q2, q3, vh, vl);
            *(uint4*)&sh.A[nxt][0][srr][skq] = vh;
            *(uint4*)&sh.A[nxt][1][srr][skq] = vl;
            *(uint4*)&sh.Bw[nxt][0][srr][skq] = pbh;
            if (TERMS == 3) *(uint4*)&sh.Bw[nxt][1][srr][skq] = pbl;
        }
        __syncthreads();
    }
}

// ---------------------------------------------------------------------------
// Persistent encoder: 64 steps, one barrier per step.
// Xe: packed u32 [2][512][608], cols: 0..64 x-input, 64 ts, 65..577 h, pad.
// ---------------------------------------------------------------------------
struct EncArgs {
    u32* Xe;
    const u16 *Weh, *Wel;
    const float* bias_e;
    float* c_e;
    float* tcat;
    const int* lens;
    const int* acts;
    const float* tsv;
    const float* act_emb;
    unsigned* cnt;
};

__global__ __launch_bounds__(256) void enc_persist(EncArgs a) {
    __shared__ GemmShared sh;
    const int bx = blockIdx.x & 31, by = blockIdx.x >> 5, row0 = by << 6;
    const int tid = threadIdx.x, lane = tid & 63, ws = tid >> 6;
    const int fr = lane & 15, quad = lane >> 4;
    unsigned expected = 0;
    const u16* Wh = a.Weh + (size_t)(bx << 6) * 608;
    const u16* Wl = a.Wel + (size_t)(bx << 6) * 608;
    float bb[4];
    #pragma unroll
    for (int g = 0; g < 4; ++g) bb[g] = a.bias_e[(bx << 6) + (g << 4) + fr];
    const int cell = (bx << 4) + fr;
    const int rbase = row0 + (ws << 4) + (quad << 2);

    for (int t = 0; t < TT; ++t) {
        const u32* XeC = a.Xe + (size_t)(t & 1) * B * 608;
        u32* XeN = a.Xe + (size_t)((t + 1) & 1) * B * 608;

        f32x4 acc[4] = {};
        gemm64p<3>(sh, XeC + (size_t)row0 * 608, 608, Wh, Wl, 608, acc);

        #pragma unroll
        for (int r = 0; r < 4; ++r) {
            int b = rbase + r;
            float gi = acc[0][r] + bb[0], gf = acc[1][r] + bb[1];
            float gg = acc[2][r] + bb[2], go = acc[3][r] + bb[3];
            float cold = a.c_e[(b << 9) + cell];
            float cn = sigm(gf) * cold + sigm(gi) * tanhf(gg);
            a.c_e[(b << 9) + cell] = cn;
            float h = sigm(go) * tanhf(cn);
            cstore32(&XeN[b * 608 + 65 + cell], packbf(h));
            if (t == a.lens[b] - 1) a.tcat[b * TDIM + 8 + cell] = h;
        }
        if (bx == 0 && t < TT - 1) {
            for (int idx = tid; idx < 64 * 65; idx += 256) {
                int r = idx / 65, cc = idx - r * 65;
                int b = row0 + r;
                float v = (cc < 64) ? a.act_emb[a.acts[(b << 6) + t + 1] * 64 + cc]
                                    : a.tsv[(b << 6) + t + 1];
                cstore32(&XeN[b * 608 + cc], packbf(v));
            }
        }
        if (t < TT - 1) gbar(a.cnt, expected);
    }
}

// ---------------------------------------------------------------------------
// Persistent decoder: 2 barriers/step.
// Xa: packed u32 [2][512][576] (0..64 ae, 64..576 h_a). Xt: [2][512][512] h_t.
// Phase A: gemm_a+cell_a; bx<4: ts-head strip -> atomic add tsP[t&1].
// Phase B: act-head (redundant per bx) + gemm_t (h_t | LDS ae2) + cell_t
//          (+Wt576*tsc rank-1), out_ts[t-1], zero tsP[(t+1)&1] (bx==5).
// ---------------------------------------------------------------------------
struct DecArgs {
    u32 *Xa, *Xt;
    const u16 *Wah, *Wal, *Wth, *Wtl;
    const float* Wt576;
    const float *base_a, *base_t;
    float *c_a, *c_t;
    const u16 *E2h, *E2l;
    const float *e2b, *act_emb;
    float *out_acts, *out_ts;
    const u16* W1h;
    const float *b1, *w2, *b2;
    float* tsP;          // [2][512]
    unsigned* cnt;
};

__global__ __launch_bounds__(256) void dec_persist(DecArgs a) {
    __shared__ GemmShared sh;
    __shared__ u16 ae2h[64][72];
    __shared__ u16 ae2l[64][72];
    const int bx = blockIdx.x & 31, by = blockIdx.x >> 5, row0 = by << 6;
    const int tid = threadIdx.x, lane = tid & 63, ws = tid >> 6;
    const int fr = lane & 15, quad = lane >> 4, ko = quad << 3;
    const int srr = tid >> 2, skq = (tid & 3) << 3;
    const bool bx0 = (bx == 0);
    unsigned expected = 0;
    const int cell = (bx << 4) + fr;
    const int rbase = row0 + (ws << 4) + (quad << 2);
    const float b2v = a.b2[0];
    float wt4[4];
    #pragma unroll
    for (int g = 0; g < 4; ++g) wt4[g] = a.Wt576[(bx << 6) + (g << 4) + fr];

    for (int t = 0; t < TT; ++t) {
        const u32* XaC = a.Xa + (size_t)(t & 1) * B * 576;
        u32* XaN = a.Xa + (size_t)((t + 1) & 1) * B * 576;
        const u32* XtC = a.Xt + (size_t)(t & 1) * B * 512;
        u32* XtN = a.Xt + (size_t)((t + 1) & 1) * B * 512;
        float* tsPc = a.tsP + ((t & 1) << 9);
        float* tsPn = a.tsP + (((t + 1) & 1) << 9);

        // ---------------- Phase A: act-LSTM gemm + cell ----------------
        {
            f32x4 acc[4] = {};
            gemm64p<3>(sh, XaC + (size_t)row0 * 576, 576,
                       a.Wah + (size_t)(bx << 6) * 576, a.Wal + (size_t)(bx << 6) * 576,
                       576, acc);
            #pragma unroll
            for (int r = 0; r < 4; ++r) {
                int b = rbase + r;
                const float* bp = a.base_a + (size_t)b * G4 + (bx << 6) + fr;
                float gi = acc[0][r] + bp[0], gf = acc[1][r] + bp[16];
                float gg = acc[2][r] + bp[32], go = acc[3][r] + bp[48];
                float cold = a.c_a[(b << 9) + cell];
                float cn = sigm(gf) * cold + sigm(gi) * tanhf(gg);
                a.c_a[(b << 9) + cell] = cn;
                float h = sigm(go) * tanhf(cn);
                cstore32(&XaN[b * 576 + 64 + cell], packbf(h));
            }
        }
        // ts-head strip (for this step's tsc), 4 blocks per row-group
        if (bx < 4 && t > 0) {
            f32x4 ac[4] = {};
            gemm64p<2>(sh, XtC + (size_t)row0 * 512, 512,
                       a.W1h + (size_t)(bx << 6) * 512, nullptr, 512, ac);
            float s0 = 0.f, s1 = 0.f, s2 = 0.f, s3 = 0.f;
            #pragma unroll
            for (int nt = 0; nt < 4; ++nt) {
                int j = (bx << 6) + (nt << 4) + fr;
                float b1v = a.b1[j], w2v = a.w2[j];
                s0 += fmaxf(ac[nt][0] + b1v, 0.f) * w2v;
                s1 += fmaxf(ac[nt][1] + b1v, 0.f) * w2v;
                s2 += fmaxf(ac[nt][2] + b1v, 0.f) * w2v;
                s3 += fmaxf(ac[nt][3] + b1v, 0.f) * w2v;
            }
            #pragma unroll
            for (int off = 1; off < 16; off <<= 1) {
                s0 += __shfl_xor(s0, off); s1 += __shfl_xor(s1, off);
                s2 += __shfl_xor(s2, off); s3 += __shfl_xor(s3, off);
            }
            if (fr == 0) {
                __hip_atomic_fetch_add(&tsPc[rbase + 0], s0, __ATOMIC_RELAXED, __HIP_MEMORY_SCOPE_AGENT);
                __hip_atomic_fetch_add(&tsPc[rbase + 1], s1, __ATOMIC_RELAXED, __HIP_MEMORY_SCOPE_AGENT);
                __hip_atomic_fetch_add(&tsPc[rbase + 2], s2, __ATOMIC_RELAXED, __HIP_MEMORY_SCOPE_AGENT);
                __hip_atomic_fetch_add(&tsPc[rbase + 3], s3, __ATOMIC_RELAXED, __HIP_MEMORY_SCOPE_AGENT);
            }
        }
        gbar(a.cnt, expected);

        // ---------------- Phase B: act head + time-LSTM ----------------
        {
            f32x4 acc[4] = {};
            gemm64p<3>(sh, XaN + (size_t)row0 * 576 + 64, 576, a.E2h, a.E2l, 512, acc);
            float e2bv[4];
            #pragma unroll
            for (int nt = 0; nt < 4; ++nt) e2bv[nt] = a.e2b[(nt << 4) + fr];
            const int rl0 = (ws << 4) + (quad << 2);
            #pragma unroll
            for (int r = 0; r < 4; ++r) {
                float l0 = acc[0][r] + e2bv[0], l1 = acc[1][r] + e2bv[1];
                float l2 = acc[2][r] + e2bv[2], l3 = acc[3][r] + e2bv[3];
                float m = fmaxf(fmaxf(l0, l1), fmaxf(l2, l3));
                #pragma unroll
                for (int off = 1; off < 16; off <<= 1) m = fmaxf(m, __shfl_xor(m, off));
                float e0 = expf(l0 - m), e1 = expf(l1 - m);
                float e2v = expf(l2 - m), e3 = expf(l3 - m);
                float sm = e0 + e1 + e2v + e3;
                #pragma unroll
                for (int off = 1; off < 16; off <<= 1) sm += __shfl_xor(sm, off);
                float bv = l0; int bc = fr;
                if (l1 > bv) { bv = l1; bc = 16 + fr; }
                if (l2 > bv) { bv = l2; bc = 32 + fr; }
                if (l3 > bv) { bv = l3; bc = 48 + fr; }
                #pragma unroll
                for (int off = 1; off < 16; off <<= 1) {
                    float ov = __shfl_xor(bv, off);
                    int oc = __shfl_xor(bc, off);
                    if (ov > bv || (ov == bv && oc < bc)) { bv = ov; bc = oc; }
                }
                int rl = rl0 + r, b = row0 + rl;
                if (bx0) {
                    float inv = 1.f / sm;
                    float* op = a.out_acts + (((size_t)(b << 6) + t) << 6);
                    op[fr] = e0 * inv; op[16 + fr] = e1 * inv;
                    op[32 + fr] = e2v * inv; op[48 + fr] = e3 * inv;
                }
                #pragma unroll
                for (int ci = 0; ci < 4; ++ci) {
                    int cc = (fr << 2) + ci;
                    float v = a.act_emb[(bc << 6) + cc];
                    u16 hh = f2bf(v), hl = f2bf(v - bf2f(hh));
                    ae2h[rl][cc] = hh; ae2l[rl][cc] = hl;
                    if (bx0) cstore32(&XaN[b * 576 + cc], (u32)hh | ((u32)hl << 16));
                }
            }
        }
        __syncthreads();

        // gemm_t: K=576 = h_t(t-1)[coherent global] | ae2[LDS]
        f32x4 acc2[4] = {};
        {
            const u32* ap = XtC + (size_t)(row0 + srr) * 512 + skq;
            const u16* wph = a.Wth + (size_t)((bx << 6) + srr) * 576 + skq;
            const u16* wpl = a.Wtl + (size_t)((bx << 6) + srr) * 576 + skq;
            {
                u64 q0 = cload64(ap), q1 = cload64(ap + 2), q2 = cload64(ap + 4), q3 = cload64(ap + 6);
                uint4 vh, vl; unpack8(q0, q1, q2, q3, vh, vl);
                *(uint4*)&sh.A[0][0][srr][skq] = vh;
                *(uint4*)&sh.A[0][1][srr][skq] = vl;
                *(uint4*)&sh.Bw[0][0][srr][skq] = *(const uint4*)wph;
                *(uint4*)&sh.Bw[0][1][srr][skq] = *(const uint4*)wpl;
            }
            __syncthreads();
            for (int i = 0; i < 18; ++i) {
                const int cur = i & 1, nxt = cur ^ 1;
                const bool pf = (i + 1 < 18);
                const bool pfA = (i + 1 < 16);
                u64 q0, q1, q2, q3; uint4 pbh, pbl;
                if (pf) {
                    int k = (i + 1) << 5;
                    if (pfA) {
                        q0 = cload64(ap + k); q1 = cload64(ap + k + 2);
                        q2 = cload64(ap + k + 4); q3 = cload64(ap + k + 6);
                    }
                    pbh = *(const uint4*)(wph + k);
                    pbl = *(const uint4*)(wpl + k);
                }
                bf16x8 ah, al;
                if (i < 16) {
                    ah = *(const bf16x8*)&sh.A[cur][0][(ws << 4) + fr][ko];
                    al = *(const bf16x8*)&sh.A[cur][1][(ws << 4) + fr][ko];
                } else {
                    int c0 = ((i - 16) << 5) + ko;
                    ah = *(const bf16x8*)&ae2h[(ws << 4) + fr][c0];
                    al = *(const bf16x8*)&ae2l[(ws << 4) + fr][c0];
                }
                #pragma unroll
                for (int nt = 0; nt < 4; ++nt) {
                    bf16x8 bh = *(const bf16x8*)&sh.Bw[cur][0][(nt << 4) + fr][ko];
                    bf16x8 bl = *(const bf16x8*)&sh.Bw[cur][1][(nt << 4) + fr][ko];
                    acc2[nt] = __builtin_amdgcn_mfma_f32_16x16x32_bf16(ah, bh, acc2[nt], 0, 0, 0);
                    acc2[nt] = __builtin_amdgcn_mfma_f32_16x16x32_bf16(ah, bl, acc2[nt], 0, 0, 0);
                    acc2[nt] = __builtin_amdgcn_mfma_f32_16x16x32_bf16(al, bh, acc2[nt], 0, 0, 0);
                }
                if (pf) {
                    if (pfA) {
                        uint4 vh, vl; unpack8(q0, q1, q2, q3, vh, vl);
                        *(uint4*)&sh.A[nxt][0][srr][skq] = vh;
                        *(uint4*)&sh.A[nxt][1][srr][skq] = vl;
                    }
                    *(uint4*)&sh.Bw[nxt][0][srr][skq] = pbh;
                    *(uint4*)&sh.Bw[nxt][1][srr][skq] = pbl;
                }
                __syncthreads();
            }
        }
        // cell_t epilogue (+ rank-1 tsc term)
        #pragma unroll
        for (int r = 0; r < 4; ++r) {
            int b = rbase + r;
            float tsc = 0.f;
            if (t > 0) tsc = cloadf(&tsPc[b]) + b2v;
            const float* bp = a.base_t + (size_t)b * G4 + (bx << 6) + fr;
            float gi = acc2[0][r] + bp[0] + wt4[0] * tsc;
            float gf = acc2[1][r] + bp[16] + wt4[1] * tsc;
            float gg = acc2[2][r] + bp[32] + wt4[2] * tsc;
            float go = acc2[3][r] + bp[48] + wt4[3] * tsc;
            float cold = a.c_t[(b << 9) + cell];
            float cn = sigm(gf) * cold + sigm(gi) * tanhf(gg);
            a.c_t[(b << 9) + cell] = cn;
            float h = sigm(go) * tanhf(cn);
            cstore32(&XtN[b * 512 + cell], packbf(h));
            if (bx0 && fr == 0 && t > 0) a.out_ts[(b << 6) + (t - 1)] = tsc;
        }
        if (bx == 5 && tid < 64) cstoref(&tsPn[row0 + tid], 0.f);
        if (t < TT - 1) gbar(a.cnt, expected);
    }
}

// Final ts output column from h_t(63) (in Xt parity 0 after the loop).
__global__ __launch_bounds__(256) void ts_tail(
    const u32* __restrict__ Xt0,
    const u16* __restrict__ W1h, const float* __restrict__ b1,
    const float* __restrict__ w2, const float* __restrict__ b2p,
    float* __restrict__ out_ts)
{
    __shared__ GemmShared sh;
    const int row0 = blockIdx.y << 6;
    const int lane = threadIdx.x & 63, ws = threadIdx.x >> 6;
    const int fr = lane & 15, quad = lane >> 4;
    float s[4] = {0.f, 0.f, 0.f, 0.f};
    for (int ncg = 0; ncg < 4; ++ncg) {
        f32x4 ac[4] = {};
        gemm64p<2>(sh, Xt0 + (size_t)row0 * 512, 512,
                   W1h + (size_t)(ncg << 6) * 512, nullptr, 512, ac);
        #pragma unroll
        for (int nt = 0; nt < 4; ++nt) {
            int j = (ncg << 6) + (nt << 4) + fr;
            float b1v = b1[j], w2v = w2[j];
            s[0] += fmaxf(ac[nt][0] + b1v, 0.f) * w2v;
            s[1] += fmaxf(ac[nt][1] + b1v, 0.f) * w2v;
            s[2] += fmaxf(ac[nt][2] + b1v, 0.f) * w2v;
            s[3] += fmaxf(ac[nt][3] + b1v, 0.f) * w2v;
        }
    }
    #pragma unroll
    for (int off = 1; off < 16; off <<= 1) {
        s[0] += __shfl_xor(s[0], off); s[1] += __shfl_xor(s[1], off);
        s[2] += __shfl_xor(s[2], off); s[3] += __shfl_xor(s[3], off);
    }
    if (fr == 0) {
        float bb2 = b2p[0];
        int rb = row0 + (ws << 4) + (quad << 2);
        #pragma unroll
        for (int r = 0; r < 4; ++r) out_ts[((rb + r) << 6) + 63] = s[r] + bb2;
    }
}

// ---------------------------------------------------------------------------
// fp32 GEMM for latent/prep: z-mode (A = Am + Av*Ae), dual-output via
// blockIdx.z, optional gate-perm W row indexing.
// ---------------------------------------------------------------------------
__device__ __forceinline__ int perm_src(int np) {
    int g = (np & 63) >> 4;
    int cell = ((np >> 6) << 4) + (np & 15);
    return (g << 9) + cell;
}

__global__ __launch_bounds__(256) void gemm_tn(
    const float* __restrict__ A, const float* __restrict__ Am,
    const float* __restrict__ Av, const float* __restrict__ Ae, int lda,
    const float* __restrict__ W1p, int ldw1,
    const float* __restrict__ W2p, int ldw2,
    int N, int K,
    const float* __restrict__ b1p, const float* __restrict__ b2p,
    float* __restrict__ C1, float* __restrict__ C2, int ldc,
    int relu, int permW)
{
    const float* W = W1p; int ldw = ldw1;
    const float* bias = b1p; float* C = C1;
    if (blockIdx.z == 1) { W = W2p; ldw = ldw2; bias = b2p; C = C2; }

    __shared__ __align__(16) float As[32][68];
    __shared__ __align__(16) float Ws[32][68];
    const int tid = threadIdx.x;
    const int tx = tid & 15, ty = tid >> 4;
    const int row0 = blockIdx.y << 6;
    const int col0 = blockIdx.x << 6;

    float acc[4][4] = {};

    for (int k0 = 0; k0 < K; k0 += 32) {
        #pragma unroll
        for (int s = 0; s < 2; ++s) {
            int f = tid + (s << 8);
            int rr = f >> 3;
            int kq = (f & 7) << 2;
            int k = k0 + kq;
            float4 v = make_float4(0.f, 0.f, 0.f, 0.f);
            size_t ro = (size_t)(row0 + rr) * (size_t)lda;
            if (Am) {
                if (k + 3 < K) {
                    float4 m = *(const float4*)(Am + ro + k);
                    float4 vv = *(const float4*)(Av + ro + k);
                    float4 e = *(const float4*)(Ae + ro + k);
                    v.x = fmaf(vv.x, e.x, m.x); v.y = fmaf(vv.y, e.y, m.y);
                    v.z = fmaf(vv.z, e.z, m.z); v.w = fmaf(vv.w, e.w, m.w);
                } else {
                    if (k + 0 < K) v.x = fmaf(Av[ro + k], Ae[ro + k], Am[ro + k]);
                    if (k + 1 < K) v.y = fmaf(Av[ro + k + 1], Ae[ro + k + 1], Am[ro + k + 1]);
                    if (k + 2 < K) v.z = fmaf(Av[ro + k + 2], Ae[ro + k + 2], Am[ro + k + 2]);
                }
            } else {
                const float* ap = A + ro;
                if (k + 3 < K) v = *(const float4*)(ap + k);
                else {
                    if (k + 0 < K) v.x = ap[k + 0];
                    if (k + 1 < K) v.y = ap[k + 1];
                    if (k + 2 < K) v.z = ap[k + 2];
                }
            }
            As[kq + 0][rr] = v.x; As[kq + 1][rr] = v.y;
            As[kq + 2][rr] = v.z; As[kq + 3][rr] = v.w;
        }
        #pragma unroll
        for (int s = 0; s < 2; ++s) {
            int f = tid + (s << 8);
            int rr = f >> 3;
            int kq = (f & 7) << 2;
            int k = k0 + kq;
            int n = col0 + rr;
            float4 v = make_float4(0.f, 0.f, 0.f, 0.f);
            if (n < N) {
                int nsrc = permW ? perm_src(n) : n;
                const float* wp = W + (size_t)nsrc * (size_t)ldw;
                if (k + 3 < K) v = *(const float4*)(wp + k);
                else {
                    if (k + 0 < K) v.x = wp[k + 0];
                    if (k + 1 < K) v.y = wp[k + 1];
                    if (k + 2 < K) v.z = wp[k + 2];
                }
            }
            Ws[kq + 0][rr] = v.x; Ws[kq + 1][rr] = v.y;
            Ws[kq + 2][rr] = v.z; Ws[kq + 3][rr] = v.w;
        }
        __syncthreads();
        #pragma unroll
        for (int k = 0; k < 32; ++k) {
            float4 av = *(const float4*)&As[k][ty << 2];
            float4 bv = *(const float4*)&Ws[k][tx << 2];
            acc[0][0] = fmaf(av.x, bv.x, acc[0][0]);
            acc[0][1] = fmaf(av.x, bv.y, acc[0][1]);
            acc[0][2] = fmaf(av.x, bv.z, acc[0][2]);
            acc[0][3] = fmaf(av.x, bv.w, acc[0][3]);
            acc[1][0] = fmaf(av.y, bv.x, acc[1][0]);
            acc[1][1] = fmaf(av.y, bv.y, acc[1][1]);
            acc[1][2] = fmaf(av.y, bv.z, acc[1][2]);
            acc[1][3] = fmaf(av.y, bv.w, acc[1][3]);
            acc[2][0] = fmaf(av.z, bv.x, acc[2][0]);
            acc[2][1] = fmaf(av.z, bv.y, acc[2][1]);
            acc[2][2] = fmaf(av.z, bv.z, acc[2][2]);
            acc[2][3] = fmaf(av.z, bv.w, acc[2][3]);
            acc[3][0] = fmaf(av.w, bv.x, acc[3][0]);
            acc[3][1] = fmaf(av.w, bv.y, acc[3][1]);
            acc[3][2] = fmaf(av.w, bv.z, acc[3][2]);
            acc[3][3] = fmaf(av.w, bv.w, acc[3][3]);
        }
        __syncthreads();
    }

    #pragma unroll
    for (int i = 0; i < 4; ++i) {
        int rr = row0 + (ty << 2) + i;
        float* cp = C + (size_t)rr * (size_t)ldc;
        #pragma unroll
        for (int j = 0; j < 4; ++j) {
            int cc = col0 + (tx << 2) + j;
            if (cc < N) {
                float v = acc[i][j];
                if (bias) v += bias[cc];
                if (relu) v = fmaxf(v, 0.f);
                cp[cc] = v;
            }
        }
    }
}

// ---------------------------------------------------------------------------
// One-shot packing: We (K=608), Wt (K=576 + col-576 extract), W1 (hi),
// E2 (hi/lo), biases.
// ---------------------------------------------------------------------------
#define N_WE (G4 * 608)
#define N_WT (G4 * 576)
#define N_W1 (256 * 512)
#define N_E2 (64 * 512)
__global__ void pack_all(
    u16* __restrict__ Weh, u16* __restrict__ Wel,
    u16* __restrict__ Wth, u16* __restrict__ Wtl, float* __restrict__ Wt576,
    u16* __restrict__ W1h,
    u16* __restrict__ E2h, u16* __restrict__ E2l,
    float* __restrict__ be, float* __restrict__ ba, float* __restrict__ bt,
    const float* __restrict__ eWih, const float* __restrict__ eWhh,
    const float* __restrict__ tWih, const float* __restrict__ tWhh,
    const float* __restrict__ ts1W, const float* __restrict__ e2W,
    const float* __restrict__ ebih, const float* __restrict__ ebhh,
    const float* __restrict__ abih, const float* __restrict__ abhh,
    const float* __restrict__ tbih, const float* __restrict__ tbhh)
{
    int idx = blockIdx.x * 256 + threadIdx.x;
    if (idx < N_WE) {
        int np = idx / 608, k = idx - np * 608;
        int n = perm_src(np);
        float v = 0.f;
        if (k < 65) v = eWih[n * 65 + k];
        else if (k < 577) v = eWhh[(n << 9) + k - 65];
        u16 h = f2bf(v); Weh[idx] = h; Wel[idx] = f2bf(v - bf2f(h));
        return;
    }
    idx -= N_WE;
    if (idx < N_WT) {
        int np = idx / 576, k = idx - np * 576;
        int n = perm_src(np);
        float v = (k < 512) ? tWhh[(n << 9) + k] : tWih[n * 585 + 520 + (k - 512)];
        u16 h = f2bf(v); Wth[idx] = h; Wtl[idx] = f2bf(v - bf2f(h));
        return;
    }
    idx -= N_WT;
    if (idx < N_W1) { W1h[idx] = f2bf(ts1W[idx]); return; }
    idx -= N_W1;
    if (idx < N_E2) {
        float v = e2W[idx];
        u16 h = f2bf(v); E2h[idx] = h; E2l[idx] = f2bf(v - bf2f(h));
        return;
    }
    idx -= N_E2;
    if (idx < G4) {
        int n = perm_src(idx);
        be[idx] = ebih[n] + ebhh[n];
        ba[idx] = abih[n] + abhh[n];
        bt[idx] = tbih[n] + tbhh[n];
        Wt576[idx] = tWih[n * 585 + 584];
    }
}

__global__ void pack_wa(u16* __restrict__ hi, u16* __restrict__ lo,
                        const float* __restrict__ wih, const float* __restrict__ whh) {
    int idx = blockIdx.x * 256 + threadIdx.x;
    if (idx >= G4 * 576) return;
    int np = idx / 576, k = idx - np * 576;
    int n = perm_src(np);
    float v = (k < 64) ? wih[n * 584 + 520 + k] : whh[(n << 9) + k - 64];
    u16 h = f2bf(v); hi[idx] = h; lo[idx] = f2bf(v - bf2f(h));
}

// ---------------------------------------------------------------------------
// init: packed X buffers, c states, lens, tcat attr, tsP, barrier counters
// (cnts[0] encoder, cnts[64] decoder — both INSIDE the 512B allocation).
// ---------------------------------------------------------------------------
__global__ __launch_bounds__(256) void init_all(
    u32* __restrict__ Xe, float* __restrict__ c_e, int* __restrict__ lens,
    float* __restrict__ tcat,
    u32* __restrict__ Xa, u32* __restrict__ Xt,
    float* __restrict__ c_a, float* __restrict__ c_t,
    float* __restrict__ tsP, unsigned* __restrict__ cnts,
    const int* __restrict__ acts, const float* __restrict__ tsv,
    const float* __restrict__ act_emb,
    const int* __restrict__ attr_cat, const float* __restrict__ attr_num,
    const float* __restrict__ attr_emb,
    const float* __restrict__ a2aW, const float* __restrict__ a2ab)
{
    int b = blockIdx.x, tid = threadIdx.x;
    for (int j = tid; j < 608; j += 256) {
        float v = 0.f;
        if (j < 64) v = act_emb[acts[b << 6] * 64 + j];
        else if (j == 64) v = tsv[b << 6];
        Xe[b * 608 + j] = packbf(v);
        if (j >= 577) Xe[512 * 608 + b * 608 + j] = 0u;
    }
    for (int j = tid; j < CF; j += 256) {
        c_e[(b << 9) + j] = 0.f; c_a[(b << 9) + j] = 0.f; c_t[(b << 9) + j] = 0.f;
        Xt[(b << 9) + j] = 0u;
    }
    for (int j = tid; j < 576; j += 256)
        Xa[b * 576 + j] = packbf((j < 64) ? act_emb[63 * 64 + j] : 0.f);
    if (tid < 64) {
        int v = acts[(b << 6) + tid];
        int m = v;
        #pragma unroll
        for (int off = 32; off; off >>= 1) m = max(m, __shfl_xor(m, off));
        unsigned long long mask = __ballot(v == m);
        if (tid == 0) lens[b] = __ffsll(mask) - 1;
    }
    if (tid < 8) {
        const float* wr = a2aW + tid * 17;
        const float* em = attr_emb + attr_cat[b] * 16;
        float s = a2ab[tid];
        #pragma unroll
        for (int k = 0; k < 16; ++k) s = fmaf(em[k], wr[k], s);
        s = fmaf(attr_num[b], wr[16], s);
        tcat[b * TDIM + tid] = fmaxf(s, 0.f);
    }
    if (b < 2) {
        for (int j = tid; j < 512; j += 256) tsP[(b << 9) + j] = 0.f;
        if (tid == 0) cnts[b * 64] = 0u;   // cnts[0]=encoder, cnts[64]=decoder
    }
}

__global__ __launch_bounds__(64) void attr_heads(
    const float* __restrict__ hid1, const float* __restrict__ hid2,
    const float* __restrict__ tc2W, const float* __restrict__ tc2b,
    const float* __restrict__ tn2W, const float* __restrict__ tn2b,
    float* __restrict__ out_cat, float* __restrict__ out_num) {
    __shared__ __align__(16) float h1[260], h2[260], sl[10];
    int b = blockIdx.x, tid = threadIdx.x;
    for (int k = tid; k < 260; k += 64) {
        h1[k] = hid1[b * 260 + k];
        h2[k] = hid2[b * 260 + k];
    }
    __syncthreads();
    if (tid < 10) {
        float l = tc2b[tid];
        const float* wr = tc2W + tid * 260;
        for (int k = 0; k < 260; ++k) l = fmaf(h1[k], wr[k], l);
        sl[tid] = l;
    }
    __syncthreads();
    if (tid < 10) {
        float m = sl[0];
        for (int i = 1; i < 10; ++i) m = fmaxf(m, sl[i]);
        float ssum = 0.f;
        for (int i = 0; i < 10; ++i) ssum += expf(sl[i] - m);
        out_cat[b * 10 + tid] = expf(sl[tid] - m) / ssum;
    }
    float p = 0.f;
    for (int k = tid; k < 260; k += 64) p = fmaf(h2[k], tn2W[k], p);
    #pragma unroll
    for (int off = 32; off; off >>= 1) p += __shfl_xor(p, off);
    if (tid == 0) out_num[b] = 1.f / (1.f + expf(-(p + tn2b[0])));
}

// ---------------------------------------------------------------------------
extern "C" void kernel_launch(void* const* d_in, const int* in_sizes, int n_in,
                              void* d_out, int out_size, void* d_ws, size_t ws_size,
                              hipStream_t stream) {
    const int*   attr_cat = (const int*)  d_in[0];
    const float* attr_num = (const float*)d_in[1];
    const int*   acts     = (const int*)  d_in[2];
    const float* tsv      = (const float*)d_in[3];
    const float* eps      = (const float*)d_in[4];
    const float* attr_emb = (const float*)d_in[5];
    const float* a2a_W    = (const float*)d_in[6];
    const float* a2a_b    = (const float*)d_in[7];
    const float* act_emb  = (const float*)d_in[8];
    const float* eWih     = (const float*)d_in[9];
    const float* eWhh     = (const float*)d_in[10];
    const float* ebih     = (const float*)d_in[11];
    const float* ebhh     = (const float*)d_in[12];
    const float* mean_W   = (const float*)d_in[13];
    const float* mean_b   = (const float*)d_in[14];
    const float* var_W    = (const float*)d_in[15];
    const float* var_b    = (const float*)d_in[16];
    const float* z2t_W    = (const float*)d_in[17];
    const float* z2t_b    = (const float*)d_in[18];
    const float* tc1_W    = (const float*)d_in[19];
    const float* tc1_b    = (const float*)d_in[20];
    const float* tc2_W    = (const float*)d_in[21];
    const float* tc2_b    = (const float*)d_in[22];
    const float* tn1_W    = (const float*)d_in[23];
    const float* tn1_b    = (const float*)d_in[24];
    const float* tn2_W    = (const float*)d_in[25];
    const float* tn2_b    = (const float*)d_in[26];
    const float* aWih     = (const float*)d_in[27];
    const float* aWhh     = (const float*)d_in[28];
    const float* abih     = (const float*)d_in[29];
    const float* abhh     = (const float*)d_in[30];
    const float* tWih     = (const float*)d_in[31];
    const float* tWhh     = (const float*)d_in[32];
    const float* tbih     = (const float*)d_in[33];
    const float* tbhh     = (const float*)d_in[34];
    const float* e2act_W  = (const float*)d_in[35];
    const float* e2act_b  = (const float*)d_in[36];
    const float* ts1_W    = (const float*)d_in[37];
    const float* ts1_b    = (const float*)d_in[38];
    const float* ts2_W    = (const float*)d_in[39];
    const float* ts2_b    = (const float*)d_in[40];

    float* out = (float*)d_out;
    float* out_cat  = out;
    float* out_num  = out + 5120;
    float* out_acts = out + 5632;
    float* out_ts   = out + 2102784;
    float* outm     = out + 2135552;
    float* outv     = out + 2201088;

    char* w = (char*)d_ws;
    auto alloc = [&](size_t bytes) { char* p = w; w += (bytes + 255) & ~(size_t)255; return p; };
    // --- persistent region ---
    u16*   Wt_hi  = (u16*)alloc((size_t)G4 * 576 * 2);
    u16*   Wt_lo  = (u16*)alloc((size_t)G4 * 576 * 2);
    float* Wt576  = (float*)alloc(G4 * 4);
    u16*   W1h    = (u16*)alloc(256 * 512 * 2);
    u16*   E2h    = (u16*)alloc(64 * 512 * 2);
    u16*   E2l    = (u16*)alloc(64 * 512 * 2);
    float* bias_e = (float*)alloc(G4 * 4);
    float* bias_a = (float*)alloc(G4 * 4);
    float* bias_t = (float*)alloc(G4 * 4);
    float* base_a = (float*)alloc((size_t)B * G4 * 4);
    float* base_t = (float*)alloc((size_t)B * G4 * 4);
    u32*   Xa     = (u32*)alloc((size_t)2 * B * 576 * 4);
    u32*   Xt     = (u32*)alloc((size_t)2 * B * 512 * 4);
    float* c_a    = (float*)alloc((size_t)B * CF * 4);
    float* c_t    = (float*)alloc((size_t)B * CF * 4);
    float* tcat   = (float*)alloc((size_t)B * TDIM * 4);
    float* t_rec  = (float*)alloc((size_t)B * TDIM * 4);
    float* hid1   = (float*)alloc((size_t)B * 260 * 4);
    float* hid2   = (float*)alloc((size_t)B * 260 * 4);
    int*   lens   = (int*)alloc(512 * 4);
    float* tsP    = (float*)alloc(2 * 512 * 4);
    unsigned* cnts = (unsigned*)alloc(512);   // 128 u32: [0]=enc ctr, [64]=dec ctr
    // --- phase overlay: encoder {We, Xe, c_e} / decoder {Wa} ---
    char* phase = w;
    u16*   We_hi  = (u16*)(phase);
    u16*   We_lo  = (u16*)(phase + (size_t)G4 * 608 * 2);
    u32*   Xe     = (u32*)(phase + (size_t)2 * G4 * 608 * 2);
    float* c_e    = (float*)(phase + (size_t)2 * G4 * 608 * 2 + (size_t)2 * B * 608 * 4);
    u16*   Wa_hi  = (u16*)(phase);
    u16*   Wa_lo  = (u16*)(phase + (size_t)G4 * 576 * 2);
    (void)ws_size; (void)in_sizes; (void)n_in; (void)out_size;

    // ---- prep ----
    {
        int total = N_WE + N_WT + N_W1 + N_E2 + G4;
        pack_all<<<(total + 255) / 256, 256, 0, stream>>>(
            We_hi, We_lo, Wt_hi, Wt_lo, Wt576, W1h, E2h, E2l,
            bias_e, bias_a, bias_t,
            eWih, eWhh, tWih, tWhh, ts1_W, e2act_W,
            ebih, ebhh, abih, abhh, tbih, tbhh);
    }
    init_all<<<B, 256, 0, stream>>>(
        Xe, c_e, lens, tcat, Xa, Xt, c_a, c_t, tsP, cnts,
        acts, tsv, act_emb, attr_cat, attr_num, attr_emb, a2a_W, a2a_b);

    // ---- encoder (1 persistent cooperative launch) ----
    EncArgs ea;
    ea.Xe = Xe; ea.Weh = We_hi; ea.Wel = We_lo; ea.bias_e = bias_e;
    ea.c_e = c_e; ea.tcat = tcat; ea.lens = lens;
    ea.acts = acts; ea.tsv = tsv; ea.act_emb = act_emb; ea.cnt = cnts;
    {
        void* args[] = { &ea };
        hipLaunchCooperativeKernel((const void*)enc_persist, dim3(256), dim3(256),
                                   args, 0, stream);
    }

    // ---- decoder weight pack (overlays We after encoder) ----
    pack_wa<<<(G4 * 576 + 255) / 256, 256, 0, stream>>>(Wa_hi, Wa_lo, aWih, aWhh);

    // ---- latent ----
    gemm_tn<<<dim3(2, 8, 2), 256, 0, stream>>>(
        tcat, nullptr, nullptr, nullptr, TDIM, mean_W, TDIM, var_W, TDIM,
        ZD, TDIM, mean_b, var_b, outm, outv, ZD, 0, 0);
    gemm_tn<<<dim3(9, 8, 1), 256, 0, stream>>>(
        nullptr, outm, outv, eps, ZD, z2t_W, ZD, nullptr, 0,
        TDIM, ZD, z2t_b, nullptr, t_rec, nullptr, TDIM, 1, 0);
    gemm_tn<<<dim3(5, 8, 2), 256, 0, stream>>>(
        t_rec, nullptr, nullptr, nullptr, TDIM, tc1_W, TDIM, tn1_W, TDIM,
        260, TDIM, tc1_b, tn1_b, hid1, hid2, 260, 1, 0);
    attr_heads<<<B, 64, 0, stream>>>(hid1, hid2, tc2_W, tc2_b, tn2_W, tn2_b, out_cat, out_num);
    gemm_tn<<<dim3(32, 8, 2), 256, 0, stream>>>(
        t_rec, nullptr, nullptr, nullptr, TDIM, aWih, 584, tWih, 585,
        G4, TDIM, bias_a, bias_t, base_a, base_t, G4, 0, 1);

    // ---- decoder (1 persistent cooperative launch) ----
    DecArgs da;
    da.Xa = Xa; da.Xt = Xt;
    da.Wah = Wa_hi; da.Wal = Wa_lo; da.Wth = Wt_hi; da.Wtl = Wt_lo; da.Wt576 = Wt576;
    da.base_a = base_a; da.base_t = base_t;
    da.c_a = c_a; da.c_t = c_t;
    da.E2h = E2h; da.E2l = E2l; da.e2b = e2act_b; da.act_emb = act_emb;
    da.out_acts = out_acts; da.out_ts = out_ts;
    da.W1h = W1h; da.b1 = ts1_b; da.w2 = ts2_W; da.b2 = ts2_b;
    da.tsP = tsP; da.cnt = cnts + 64;  // own cacheline, inside alloc, zeroed
    {
        void* args[] = { &da };
        hipLaunchCooperativeKernel((const void*)dec_persist, dim3(256), dim3(256),
                                   args, 0, stream);
    }
    ts_tail<<<dim3(1, 8), 256, 0, stream>>>(Xt, W1h, ts1_b, ts2_W, ts2_b, out_ts);
}

// Round 8
// 6202.415 us; speedup vs baseline: 1.0893x; 1.0893x over previous
//
#include <hip/hip_runtime.h>
#include <math.h>

// ---------------------------------------------------------------------------
// VAE_14482629722138 — round 8: persistent cooperative kernels with 512-thread
// blocks (8 waves = 2/SIMD for latency hiding). Each GEMM splits K across two
// 4-wave groups with separate LDS double-buffers; partials combined via LDS.
// Fence-free coherence (relaxed agent atomics, sc1) + monotonic barrier kept
// from round 7 (HW-verified). Encoder K padded to 640 for uniform group iters.
// ts_tail folded into decoder. B=512, T=64, CF=512, ZD=128, TDIM=520.
// ---------------------------------------------------------------------------

#define B 512
#define TT 64
#define CF 512
#define G4 2048
#define ZD 128
#define TDIM 520

typedef unsigned short u16;
typedef unsigned int u32;
typedef unsigned long long u64;
typedef short bf16x8 __attribute__((ext_vector_type(8)));
typedef float f32x4 __attribute__((ext_vector_type(4)));

__device__ __forceinline__ float sigm(float x) { return 1.f / (1.f + expf(-x)); }
__device__ __forceinline__ u16 f2bf(float f) {
    unsigned u = __float_as_uint(f);
    u += 0x7fffu + ((u >> 16) & 1u);
    return (u16)(u >> 16);
}
__device__ __forceinline__ float bf2f(u16 s) { return __uint_as_float(((unsigned)s) << 16); }
__device__ __forceinline__ u32 packbf(float v) {
    u16 h = f2bf(v);
    u16 l = f2bf(v - bf2f(h));
    return (u32)h | ((u32)l << 16);
}

// coherent (cross-XCD) access helpers: relaxed agent atomics -> sc1, no fences
__device__ __forceinline__ u64 cload64(const u32* p) {
    return __hip_atomic_load((const u64*)p, __ATOMIC_RELAXED, __HIP_MEMORY_SCOPE_AGENT);
}
__device__ __forceinline__ void cstore32(u32* p, u32 v) {
    __hip_atomic_store(p, v, __ATOMIC_RELAXED, __HIP_MEMORY_SCOPE_AGENT);
}
__device__ __forceinline__ float cloadf(const float* p) {
    return __hip_atomic_load(p, __ATOMIC_RELAXED, __HIP_MEMORY_SCOPE_AGENT);
}
__device__ __forceinline__ void cstoref(float* p, float v) {
    __hip_atomic_store(p, v, __ATOMIC_RELAXED, __HIP_MEMORY_SCOPE_AGENT);
}

// Monotonic grid barrier (HW-verified in rounds 6/7).
__device__ __forceinline__ void gbar(unsigned* cnt, unsigned& expected) {
    expected += 256u;
    __syncthreads();
    if (threadIdx.x == 0) {
        __builtin_amdgcn_s_waitcnt(0);
        asm volatile("" ::: "memory");
        __hip_atomic_fetch_add(cnt, 1u, __ATOMIC_RELAXED, __HIP_MEMORY_SCOPE_AGENT);
        long sp = 0;
        while (__hip_atomic_load(cnt, __ATOMIC_RELAXED, __HIP_MEMORY_SCOPE_AGENT) < expected) {
            __builtin_amdgcn_s_sleep(1);
            if (++sp > 200000000L) break;
        }
        asm volatile("" ::: "memory");
    }
    __syncthreads();
}

struct __align__(16) GemmShared {
    u16 A[2][2][64][40];   // [dbuf][hi/lo][row][k(+pad)]
    u16 Bw[2][2][64][40];
};

__device__ __forceinline__ void unpack8(u64 q0, u64 q1, u64 q2, u64 q3,
                                        uint4& vh, uint4& vl) {
    u32 w0 = (u32)q0, w1 = (u32)(q0 >> 32), w2 = (u32)q1, w3 = (u32)(q1 >> 32);
    u32 w4 = (u32)q2, w5 = (u32)(q2 >> 32), w6 = (u32)q3, w7 = (u32)(q3 >> 32);
    vh.x = (w0 & 0xffffu) | (w1 << 16); vh.y = (w2 & 0xffffu) | (w3 << 16);
    vh.z = (w4 & 0xffffu) | (w5 << 16); vh.w = (w6 & 0xffffu) | (w7 << 16);
    vl.x = (w0 >> 16) | (w1 & 0xffff0000u); vl.y = (w2 >> 16) | (w3 & 0xffff0000u);
    vl.z = (w4 >> 16) | (w5 & 0xffff0000u); vl.w = (w6 >> 16) | (w7 & 0xffff0000u);
}

// ---------------------------------------------------------------------------
// 8-wave 64x64 MFMA tile: group g = tid>>8 handles K-half [g*K/2,(g+1)*K/2) in
// its own LDS double-buffer; partials combined via `part` (group0 ends with
// the full accumulator). K must be divisible by 64. A: packed-u32 coherent;
// B: u16 cached. TERMS=3: AhBh+AhBl+AlBh. TERMS=2: AhBh+AlBh.
// acc[nt][r] (group0): row = ws*16+quad*4+r, col = nt*16+fr.
// ---------------------------------------------------------------------------
template<int TERMS>
__device__ __forceinline__ void gemm512(
    GemmShared* shg, float* part,
    const u32* __restrict__ Ap, int lda,
    const u16* __restrict__ Bh, const u16* __restrict__ Bl, int K,
    f32x4 acc[4])
{
    const int tid = threadIdx.x;
    const int g = tid >> 8, t256 = tid & 255;
    const int lane = tid & 63, ws = (tid >> 6) & 3;
    const int fr = lane & 15, quad = lane >> 4, ko = quad << 3;
    const int srr = t256 >> 2, skq = (t256 & 3) << 3;
    GemmShared& sh = shg[g];
    const int half = K >> 1;
    const int kbase = g * half;
    const int niter = half >> 5;
    const u32* ap = Ap + srr * lda + kbase + skq;
    const u16* wph = Bh + srr * K + kbase + skq;
    const u16* wpl = (TERMS == 3) ? (Bl + srr * K + kbase + skq) : (const u16*)0;
    {
        u64 q0 = cload64(ap), q1 = cload64(ap + 2), q2 = cload64(ap + 4), q3 = cload64(ap + 6);
        uint4 vh, vl; unpack8(q0, q1, q2, q3, vh, vl);
        *(uint4*)&sh.A[0][0][srr][skq] = vh;
        *(uint4*)&sh.A[0][1][srr][skq] = vl;
        *(uint4*)&sh.Bw[0][0][srr][skq] = *(const uint4*)wph;
        if (TERMS == 3) *(uint4*)&sh.Bw[0][1][srr][skq] = *(const uint4*)wpl;
    }
    __syncthreads();
    for (int i = 0; i < niter; ++i) {
        const int cur = i & 1, nxt = cur ^ 1;
        const bool pf = (i + 1 < niter);
        u64 q0, q1, q2, q3; uint4 pbh, pbl;
        if (pf) {
            int k = (i + 1) << 5;
            q0 = cload64(ap + k); q1 = cload64(ap + k + 2);
            q2 = cload64(ap + k + 4); q3 = cload64(ap + k + 6);
            pbh = *(const uint4*)(wph + k);
            if (TERMS == 3) pbl = *(const uint4*)(wpl + k);
        }
        bf16x8 ah = *(const bf16x8*)&sh.A[cur][0][(ws << 4) + fr][ko];
        bf16x8 al = *(const bf16x8*)&sh.A[cur][1][(ws << 4) + fr][ko];
        #pragma unroll
        for (int nt = 0; nt < 4; ++nt) {
            bf16x8 bh = *(const bf16x8*)&sh.Bw[cur][0][(nt << 4) + fr][ko];
            acc[nt] = __builtin_amdgcn_mfma_f32_16x16x32_bf16(ah, bh, acc[nt], 0, 0, 0);
            if (TERMS == 3) {
                bf16x8 bl = *(const bf16x8*)&sh.Bw[cur][1][(nt << 4) + fr][ko];
                acc[nt] = __builtin_amdgcn_mfma_f32_16x16x32_bf16(ah, bl, acc[nt], 0, 0, 0);
            }
            acc[nt] = __builtin_amdgcn_mfma_f32_16x16x32_bf16(al, bh, acc[nt], 0, 0, 0);
        }
        if (pf) {
            uint4 vh, vl; unpack8(q0, q1, q2, q3, vh, vl);
            *(uint4*)&sh.A[nxt][0][srr][skq] = vh;
            *(uint4*)&sh.A[nxt][1][srr][skq] = vl;
            *(uint4*)&sh.Bw[nxt][0][srr][skq] = pbh;
            if (TERMS == 3) *(uint4*)&sh.Bw[nxt][1][srr][skq] = pbl;
        }
        __syncthreads();
    }
    // cross-group partial combine (last loop iteration ended with a sync)
    if (g == 1) {
        #pragma unroll
        for (int j = 0; j < 16; ++j) part[t256 * 17 + j] = acc[j >> 2][j & 3];
    }
    __syncthreads();
    if (g == 0) {
        #pragma unroll
        for (int j = 0; j < 16; ++j) acc[j >> 2][j & 3] += part[t256 * 17 + j];
    }
}

// ---------------------------------------------------------------------------
// Persistent encoder: 64 steps, one barrier per step. Xe packed u32
// [2][512][640]: 0..64 x-input, 64 ts, 65..577 h, 577..640 zero pad.
// ---------------------------------------------------------------------------
struct EncArgs {
    u32* Xe;
    const u16 *Weh, *Wel;
    const float* bias_e;
    float* c_e;
    float* tcat;
    const int* lens;
    const int* acts;
    const float* tsv;
    const float* act_emb;
    unsigned* cnt;
};

__global__ __launch_bounds__(512) void enc_persist(EncArgs a) {
    __shared__ __align__(16) GemmShared shg[2];
    __shared__ __align__(16) float part[256 * 17];
    const int tid = threadIdx.x;
    const int g = tid >> 8;
    const int lane = tid & 63, ws = (tid >> 6) & 3;
    const int fr = lane & 15, quad = lane >> 4;
    const int bx = blockIdx.x & 31, by = blockIdx.x >> 5, row0 = by << 6;
    unsigned expected = 0;
    const u16* Wh = a.Weh + (size_t)(bx << 6) * 640;
    const u16* Wl = a.Wel + (size_t)(bx << 6) * 640;
    float bb[4];
    #pragma unroll
    for (int g4 = 0; g4 < 4; ++g4) bb[g4] = a.bias_e[(bx << 6) + (g4 << 4) + fr];
    const int cell = (bx << 4) + fr;
    const int rbase = row0 + (ws << 4) + (quad << 2);

    for (int t = 0; t < TT; ++t) {
        const u32* XeC = a.Xe + (size_t)(t & 1) * B * 640;
        u32* XeN = a.Xe + (size_t)((t + 1) & 1) * B * 640;

        f32x4 acc[4] = {};
        gemm512<3>(shg, part, XeC + (size_t)row0 * 640, 640, Wh, Wl, 640, acc);

        if (g == 0) {
            #pragma unroll
            for (int r = 0; r < 4; ++r) {
                int b = rbase + r;
                float gi = acc[0][r] + bb[0], gf = acc[1][r] + bb[1];
                float gg = acc[2][r] + bb[2], go = acc[3][r] + bb[3];
                float cold = a.c_e[(b << 9) + cell];
                float cn = sigm(gf) * cold + sigm(gi) * tanhf(gg);
                a.c_e[(b << 9) + cell] = cn;
                float h = sigm(go) * tanhf(cn);
                cstore32(&XeN[b * 640 + 65 + cell], packbf(h));
                if (t == a.lens[b] - 1) a.tcat[b * TDIM + 8 + cell] = h;
            }
        }
        if (bx == 0 && t < TT - 1) {
            for (int idx = tid; idx < 64 * 65; idx += 512) {
                int r = idx / 65, cc = idx - r * 65;
                int b = row0 + r;
                float v = (cc < 64) ? a.act_emb[a.acts[(b << 6) + t + 1] * 64 + cc]
                                    : a.tsv[(b << 6) + t + 1];
                cstore32(&XeN[b * 640 + cc], packbf(v));
            }
        }
        if (t < TT - 1) gbar(a.cnt, expected);
    }
}

// ---------------------------------------------------------------------------
// Persistent decoder: 2 barriers/step + 2 post-loop (final ts column).
// Xa u32 [2][512][576] (0..64 ae, 64..576 h_a). Xt u32 [2][512][512] h_t.
// ---------------------------------------------------------------------------
struct DecArgs {
    u32 *Xa, *Xt;
    const u16 *Wah, *Wal, *Wth, *Wtl;
    const float* Wt576;
    const float *base_a, *base_t;
    float *c_a, *c_t;
    const u16 *E2h, *E2l;
    const float *e2b, *act_emb;
    float *out_acts, *out_ts;
    const u16* W1h;
    const float *b1, *w2, *b2;
    float* tsP;          // [2][512]
    unsigned* cnt;
};

__global__ __launch_bounds__(512) void dec_persist(DecArgs a) {
    __shared__ __align__(16) GemmShared shg[2];
    __shared__ __align__(16) float part[256 * 17];
    __shared__ __align__(16) u16 ae2h[64][72];
    __shared__ __align__(16) u16 ae2l[64][72];
    const int tid = threadIdx.x;
    const int g = tid >> 8, t256 = tid & 255;
    const int lane = tid & 63, ws = (tid >> 6) & 3;
    const int fr = lane & 15, quad = lane >> 4, ko = quad << 3;
    const int srr = t256 >> 2, skq = (t256 & 3) << 3;
    const int bx = blockIdx.x & 31, by = blockIdx.x >> 5, row0 = by << 6;
    const bool bx0 = (bx == 0);
    unsigned expected = 0;
    const int cell = (bx << 4) + fr;
    const int rbase = row0 + (ws << 4) + (quad << 2);
    const float b2v = a.b2[0];
    float wt4[4];
    #pragma unroll
    for (int g4 = 0; g4 < 4; ++g4) wt4[g4] = a.Wt576[(bx << 6) + (g4 << 4) + fr];

    for (int t = 0; t < TT; ++t) {
        const u32* XaC = a.Xa + (size_t)(t & 1) * B * 576;
        u32* XaN = a.Xa + (size_t)((t + 1) & 1) * B * 576;
        const u32* XtC = a.Xt + (size_t)(t & 1) * B * 512;
        u32* XtN = a.Xt + (size_t)((t + 1) & 1) * B * 512;
        float* tsPc = a.tsP + ((t & 1) << 9);
        float* tsPn = a.tsP + (((t + 1) & 1) << 9);

        // ---------------- Phase A: act-LSTM gemm + cell ----------------
        {
            f32x4 acc[4] = {};
            gemm512<3>(shg, part, XaC + (size_t)row0 * 576, 576,
                       a.Wah + (size_t)(bx << 6) * 576, a.Wal + (size_t)(bx << 6) * 576,
                       576, acc);
            if (g == 0) {
                #pragma unroll
                for (int r = 0; r < 4; ++r) {
                    int b = rbase + r;
                    const float* bp = a.base_a + (size_t)b * G4 + (bx << 6) + fr;
                    float gi = acc[0][r] + bp[0], gf = acc[1][r] + bp[16];
                    float gg = acc[2][r] + bp[32], go = acc[3][r] + bp[48];
                    float cold = a.c_a[(b << 9) + cell];
                    float cn = sigm(gf) * cold + sigm(gi) * tanhf(gg);
                    a.c_a[(b << 9) + cell] = cn;
                    float h = sigm(go) * tanhf(cn);
                    cstore32(&XaN[b * 576 + 64 + cell], packbf(h));
                }
            }
        }
        // ts-head strip (this step's tsc), blocks bx<4 per row-group
        if (bx < 4 && t > 0) {
            f32x4 ac[4] = {};
            gemm512<2>(shg, part, XtC + (size_t)row0 * 512, 512,
                       a.W1h + (size_t)(bx << 6) * 512, nullptr, 512, ac);
            if (g == 0) {
                float s0 = 0.f, s1 = 0.f, s2 = 0.f, s3 = 0.f;
                #pragma unroll
                for (int nt = 0; nt < 4; ++nt) {
                    int j = (bx << 6) + (nt << 4) + fr;
                    float b1v = a.b1[j], w2v = a.w2[j];
                    s0 += fmaxf(ac[nt][0] + b1v, 0.f) * w2v;
                    s1 += fmaxf(ac[nt][1] + b1v, 0.f) * w2v;
                    s2 += fmaxf(ac[nt][2] + b1v, 0.f) * w2v;
                    s3 += fmaxf(ac[nt][3] + b1v, 0.f) * w2v;
                }
                #pragma unroll
                for (int off = 1; off < 16; off <<= 1) {
                    s0 += __shfl_xor(s0, off); s1 += __shfl_xor(s1, off);
                    s2 += __shfl_xor(s2, off); s3 += __shfl_xor(s3, off);
                }
                if (fr == 0) {
                    __hip_atomic_fetch_add(&tsPc[rbase + 0], s0, __ATOMIC_RELAXED, __HIP_MEMORY_SCOPE_AGENT);
                    __hip_atomic_fetch_add(&tsPc[rbase + 1], s1, __ATOMIC_RELAXED, __HIP_MEMORY_SCOPE_AGENT);
                    __hip_atomic_fetch_add(&tsPc[rbase + 2], s2, __ATOMIC_RELAXED, __HIP_MEMORY_SCOPE_AGENT);
                    __hip_atomic_fetch_add(&tsPc[rbase + 3], s3, __ATOMIC_RELAXED, __HIP_MEMORY_SCOPE_AGENT);
                }
            }
        }
        gbar(a.cnt, expected);

        // ---------------- Phase B: act head + time-LSTM ----------------
        {
            f32x4 acc[4] = {};
            gemm512<3>(shg, part, XaN + (size_t)row0 * 576 + 64, 576, a.E2h, a.E2l, 512, acc);
            if (g == 0) {
                float e2bv[4];
                #pragma unroll
                for (int nt = 0; nt < 4; ++nt) e2bv[nt] = a.e2b[(nt << 4) + fr];
                const int rl0 = (ws << 4) + (quad << 2);
                #pragma unroll
                for (int r = 0; r < 4; ++r) {
                    float l0 = acc[0][r] + e2bv[0], l1 = acc[1][r] + e2bv[1];
                    float l2 = acc[2][r] + e2bv[2], l3 = acc[3][r] + e2bv[3];
                    float m = fmaxf(fmaxf(l0, l1), fmaxf(l2, l3));
                    #pragma unroll
                    for (int off = 1; off < 16; off <<= 1) m = fmaxf(m, __shfl_xor(m, off));
                    float e0 = expf(l0 - m), e1 = expf(l1 - m);
                    float e2v = expf(l2 - m), e3 = expf(l3 - m);
                    float sm = e0 + e1 + e2v + e3;
                    #pragma unroll
                    for (int off = 1; off < 16; off <<= 1) sm += __shfl_xor(sm, off);
                    float bv = l0; int bc = fr;
                    if (l1 > bv) { bv = l1; bc = 16 + fr; }
                    if (l2 > bv) { bv = l2; bc = 32 + fr; }
                    if (l3 > bv) { bv = l3; bc = 48 + fr; }
                    #pragma unroll
                    for (int off = 1; off < 16; off <<= 1) {
                        float ov = __shfl_xor(bv, off);
                        int oc = __shfl_xor(bc, off);
                        if (ov > bv || (ov == bv && oc < bc)) { bv = ov; bc = oc; }
                    }
                    int rl = rl0 + r, b = row0 + rl;
                    if (bx0) {
                        float inv = 1.f / sm;
                        float* op = a.out_acts + (((size_t)(b << 6) + t) << 6);
                        op[fr] = e0 * inv; op[16 + fr] = e1 * inv;
                        op[32 + fr] = e2v * inv; op[48 + fr] = e3 * inv;
                    }
                    #pragma unroll
                    for (int ci = 0; ci < 4; ++ci) {
                        int cc = (fr << 2) + ci;
                        float v = a.act_emb[(bc << 6) + cc];
                        u16 hh = f2bf(v), hl = f2bf(v - bf2f(hh));
                        ae2h[rl][cc] = hh; ae2l[rl][cc] = hl;
                        if (bx0) cstore32(&XaN[b * 576 + cc], (u32)hh | ((u32)hl << 16));
                    }
                }
            }
        }
        __syncthreads();   // ae2 visible to group1's gemm_t tail iters

        // gemm_t: K=576, halves 288/288; group1 iters with k0>=512 take
        // A-fragments from ae2 LDS instead of global.
        f32x4 acc2[4] = {};
        {
            GemmShared& sh = shg[g];
            const int kbase = g * 288;
            const u32* ap = XtC + (size_t)(row0 + srr) * 512 + kbase + skq;
            const u16* wph = a.Wth + (size_t)((bx << 6) + srr) * 576 + kbase + skq;
            const u16* wpl = a.Wtl + (size_t)((bx << 6) + srr) * 576 + kbase + skq;
            {
                u64 q0 = cload64(ap), q1 = cload64(ap + 2), q2 = cload64(ap + 4), q3 = cload64(ap + 6);
                uint4 vh, vl; unpack8(q0, q1, q2, q3, vh, vl);
                *(uint4*)&sh.A[0][0][srr][skq] = vh;
                *(uint4*)&sh.A[0][1][srr][skq] = vl;
                *(uint4*)&sh.Bw[0][0][srr][skq] = *(const uint4*)wph;
                *(uint4*)&sh.Bw[0][1][srr][skq] = *(const uint4*)wpl;
            }
            __syncthreads();
            for (int i = 0; i < 9; ++i) {
                const int cur = i & 1, nxt = cur ^ 1;
                const int k0 = kbase + (i << 5);
                const bool pf = (i + 1 < 9);
                const int k0n = kbase + ((i + 1) << 5);
                const bool pfA = pf && (k0n < 512);
                u64 q0, q1, q2, q3; uint4 pbh, pbl;
                if (pf) {
                    int k = (i + 1) << 5;
                    if (pfA) {
                        q0 = cload64(ap + k); q1 = cload64(ap + k + 2);
                        q2 = cload64(ap + k + 4); q3 = cload64(ap + k + 6);
                    }
                    pbh = *(const uint4*)(wph + k);
                    pbl = *(const uint4*)(wpl + k);
                }
                bf16x8 ah, al;
                if (g == 1 && k0 >= 512) {
                    int c0 = (k0 - 512) + ko;
                    ah = *(const bf16x8*)&ae2h[(ws << 4) + fr][c0];
                    al = *(const bf16x8*)&ae2l[(ws << 4) + fr][c0];
                } else {
                    ah = *(const bf16x8*)&sh.A[cur][0][(ws << 4) + fr][ko];
                    al = *(const bf16x8*)&sh.A[cur][1][(ws << 4) + fr][ko];
                }
                #pragma unroll
                for (int nt = 0; nt < 4; ++nt) {
                    bf16x8 bh = *(const bf16x8*)&sh.Bw[cur][0][(nt << 4) + fr][ko];
                    bf16x8 bl = *(const bf16x8*)&sh.Bw[cur][1][(nt << 4) + fr][ko];
                    acc2[nt] = __builtin_amdgcn_mfma_f32_16x16x32_bf16(ah, bh, acc2[nt], 0, 0, 0);
                    acc2[nt] = __builtin_amdgcn_mfma_f32_16x16x32_bf16(ah, bl, acc2[nt], 0, 0, 0);
                    acc2[nt] = __builtin_amdgcn_mfma_f32_16x16x32_bf16(al, bh, acc2[nt], 0, 0, 0);
                }
                if (pf) {
                    if (pfA) {
                        uint4 vh, vl; unpack8(q0, q1, q2, q3, vh, vl);
                        *(uint4*)&sh.A[nxt][0][srr][skq] = vh;
                        *(uint4*)&sh.A[nxt][1][srr][skq] = vl;
                    }
                    *(uint4*)&sh.Bw[nxt][0][srr][skq] = pbh;
                    *(uint4*)&sh.Bw[nxt][1][srr][skq] = pbl;
                }
                __syncthreads();
            }
            if (g == 1) {
                #pragma unroll
                for (int j = 0; j < 16; ++j) part[t256 * 17 + j] = acc2[j >> 2][j & 3];
            }
            __syncthreads();
            if (g == 0) {
                #pragma unroll
                for (int j = 0; j < 16; ++j) acc2[j >> 2][j & 3] += part[t256 * 17 + j];
            }
        }
        // cell_t epilogue (+ rank-1 tsc term), group0
        if (g == 0) {
            #pragma unroll
            for (int r = 0; r < 4; ++r) {
                int b = rbase + r;
                float tsc = 0.f;
                if (t > 0) tsc = cloadf(&tsPc[b]) + b2v;
                const float* bp = a.base_t + (size_t)b * G4 + (bx << 6) + fr;
                float gi = acc2[0][r] + bp[0] + wt4[0] * tsc;
                float gf = acc2[1][r] + bp[16] + wt4[1] * tsc;
                float gg = acc2[2][r] + bp[32] + wt4[2] * tsc;
                float go = acc2[3][r] + bp[48] + wt4[3] * tsc;
                float cold = a.c_t[(b << 9) + cell];
                float cn = sigm(gf) * cold + sigm(gi) * tanhf(gg);
                a.c_t[(b << 9) + cell] = cn;
                float h = sigm(go) * tanhf(cn);
                cstore32(&XtN[b * 512 + cell], packbf(h));
                if (bx0 && fr == 0 && t > 0) a.out_ts[(b << 6) + (t - 1)] = tsc;
            }
        }
        if (bx == 5 && tid < 64) cstoref(&tsPn[row0 + tid], 0.f);
        if (t < TT - 1) gbar(a.cnt, expected);
    }

    // ---- final ts column (h_t(63) lives in Xt parity 0) ----
    gbar(a.cnt, expected);
    if (bx < 4) {
        f32x4 ac[4] = {};
        gemm512<2>(shg, part, a.Xt + (size_t)row0 * 512, 512,
                   a.W1h + (size_t)(bx << 6) * 512, nullptr, 512, ac);
        if (g == 0) {
            float s0 = 0.f, s1 = 0.f, s2 = 0.f, s3 = 0.f;
            #pragma unroll
            for (int nt = 0; nt < 4; ++nt) {
                int j = (bx << 6) + (nt << 4) + fr;
                float b1v = a.b1[j], w2v = a.w2[j];
                s0 += fmaxf(ac[nt][0] + b1v, 0.f) * w2v;
                s1 += fmaxf(ac[nt][1] + b1v, 0.f) * w2v;
                s2 += fmaxf(ac[nt][2] + b1v, 0.f) * w2v;
                s3 += fmaxf(ac[nt][3] + b1v, 0.f) * w2v;
            }
            #pragma unroll
            for (int off = 1; off < 16; off <<= 1) {
                s0 += __shfl_xor(s0, off); s1 += __shfl_xor(s1, off);
                s2 += __shfl_xor(s2, off); s3 += __shfl_xor(s3, off);
            }
            if (fr == 0) {
                __hip_atomic_fetch_add(&a.tsP[rbase + 0], s0, __ATOMIC_RELAXED, __HIP_MEMORY_SCOPE_AGENT);
                __hip_atomic_fetch_add(&a.tsP[rbase + 1], s1, __ATOMIC_RELAXED, __HIP_MEMORY_SCOPE_AGENT);
                __hip_atomic_fetch_add(&a.tsP[rbase + 2], s2, __ATOMIC_RELAXED, __HIP_MEMORY_SCOPE_AGENT);
                __hip_atomic_fetch_add(&a.tsP[rbase + 3], s3, __ATOMIC_RELAXED, __HIP_MEMORY_SCOPE_AGENT);
            }
        }
    }
    gbar(a.cnt, expected);
    if (bx0 && g == 0 && fr == 0) {
        #pragma unroll
        for (int r = 0; r < 4; ++r)
            a.out_ts[((rbase + r) << 6) + 63] = cloadf(&a.tsP[rbase + r]) + b2v;
    }
}

// ---------------------------------------------------------------------------
// fp32 GEMM for latent/prep: z-mode (A = Am + Av*Ae), dual-output via
// blockIdx.z, optional gate-perm W row indexing. (256 threads, unchanged.)
// ---------------------------------------------------------------------------
__device__ __forceinline__ int perm_src(int np) {
    int g = (np & 63) >> 4;
    int cell = ((np >> 6) << 4) + (np & 15);
    return (g << 9) + cell;
}

__global__ __launch_bounds__(256) void gemm_tn(
    const float* __restrict__ A, const float* __restrict__ Am,
    const float* __restrict__ Av, const float* __restrict__ Ae, int lda,
    const float* __restrict__ W1p, int ldw1,
    const float* __restrict__ W2p, int ldw2,
    int N, int K,
    const float* __restrict__ b1p, const float* __restrict__ b2p,
    float* __restrict__ C1, float* __restrict__ C2, int ldc,
    int relu, int permW)
{
    const float* W = W1p; int ldw = ldw1;
    const float* bias = b1p; float* C = C1;
    if (blockIdx.z == 1) { W = W2p; ldw = ldw2; bias = b2p; C = C2; }

    __shared__ __align__(16) float As[32][68];
    __shared__ __align__(16) float Ws[32][68];
    const int tid = threadIdx.x;
    const int tx = tid & 15, ty = tid >> 4;
    const int row0 = blockIdx.y << 6;
    const int col0 = blockIdx.x << 6;

    float acc[4][4] = {};

    for (int k0 = 0; k0 < K; k0 += 32) {
        #pragma unroll
        for (int s = 0; s < 2; ++s) {
            int f = tid + (s << 8);
            int rr = f >> 3;
            int kq = (f & 7) << 2;
            int k = k0 + kq;
            float4 v = make_float4(0.f, 0.f, 0.f, 0.f);
            size_t ro = (size_t)(row0 + rr) * (size_t)lda;
            if (Am) {
                if (k + 3 < K) {
                    float4 m = *(const float4*)(Am + ro + k);
                    float4 vv = *(const float4*)(Av + ro + k);
                    float4 e = *(const float4*)(Ae + ro + k);
                    v.x = fmaf(vv.x, e.x, m.x); v.y = fmaf(vv.y, e.y, m.y);
                    v.z = fmaf(vv.z, e.z, m.z); v.w = fmaf(vv.w, e.w, m.w);
                } else {
                    if (k + 0 < K) v.x = fmaf(Av[ro + k], Ae[ro + k], Am[ro + k]);
                    if (k + 1 < K) v.y = fmaf(Av[ro + k + 1], Ae[ro + k + 1], Am[ro + k + 1]);
                    if (k + 2 < K) v.z = fmaf(Av[ro + k + 2], Ae[ro + k + 2], Am[ro + k + 2]);
                }
            } else {
                const float* ap = A + ro;
                if (k + 3 < K) v = *(const float4*)(ap + k);
                else {
                    if (k + 0 < K) v.x = ap[k + 0];
                    if (k + 1 < K) v.y = ap[k + 1];
                    if (k + 2 < K) v.z = ap[k + 2];
                }
            }
            As[kq + 0][rr] = v.x; As[kq + 1][rr] = v.y;
            As[kq + 2][rr] = v.z; As[kq + 3][rr] = v.w;
        }
        #pragma unroll
        for (int s = 0; s < 2; ++s) {
            int f = tid + (s << 8);
            int rr = f >> 3;
            int kq = (f & 7) << 2;
            int k = k0 + kq;
            int n = col0 + rr;
            float4 v = make_float4(0.f, 0.f, 0.f, 0.f);
            if (n < N) {
                int nsrc = permW ? perm_src(n) : n;
                const float* wp = W + (size_t)nsrc * (size_t)ldw;
                if (k + 3 < K) v = *(const float4*)(wp + k);
                else {
                    if (k + 0 < K) v.x = wp[k + 0];
                    if (k + 1 < K) v.y = wp[k + 1];
                    if (k + 2 < K) v.z = wp[k + 2];
                }
            }
            Ws[kq + 0][rr] = v.x; Ws[kq + 1][rr] = v.y;
            Ws[kq + 2][rr] = v.z; Ws[kq + 3][rr] = v.w;
        }
        __syncthreads();
        #pragma unroll
        for (int k = 0; k < 32; ++k) {
            float4 av = *(const float4*)&As[k][ty << 2];
            float4 bv = *(const float4*)&Ws[k][tx << 2];
            acc[0][0] = fmaf(av.x, bv.x, acc[0][0]);
            acc[0][1] = fmaf(av.x, bv.y, acc[0][1]);
            acc[0][2] = fmaf(av.x, bv.z, acc[0][2]);
            acc[0][3] = fmaf(av.x, bv.w, acc[0][3]);
            acc[1][0] = fmaf(av.y, bv.x, acc[1][0]);
            acc[1][1] = fmaf(av.y, bv.y, acc[1][1]);
            acc[1][2] = fmaf(av.y, bv.z, acc[1][2]);
            acc[1][3] = fmaf(av.y, bv.w, acc[1][3]);
            acc[2][0] = fmaf(av.z, bv.x, acc[2][0]);
            acc[2][1] = fmaf(av.z, bv.y, acc[2][1]);
            acc[2][2] = fmaf(av.z, bv.z, acc[2][2]);
            acc[2][3] = fmaf(av.z, bv.w, acc[2][3]);
            acc[3][0] = fmaf(av.w, bv.x, acc[3][0]);
            acc[3][1] = fmaf(av.w, bv.y, acc[3][1]);
            acc[3][2] = fmaf(av.w, bv.z, acc[3][2]);
            acc[3][3] = fmaf(av.w, bv.w, acc[3][3]);
        }
        __syncthreads();
    }

    #pragma unroll
    for (int i = 0; i < 4; ++i) {
        int rr = row0 + (ty << 2) + i;
        float* cp = C + (size_t)rr * (size_t)ldc;
        #pragma unroll
        for (int j = 0; j < 4; ++j) {
            int cc = col0 + (tx << 2) + j;
            if (cc < N) {
                float v = acc[i][j];
                if (bias) v += bias[cc];
                if (relu) v = fmaxf(v, 0.f);
                cp[cc] = v;
            }
        }
    }
}

// ---------------------------------------------------------------------------
// One-shot packing: We (K=640 padded), Wt (K=576 + col-576 extract), W1 (hi),
// E2 (hi/lo), biases.
// ---------------------------------------------------------------------------
#define N_WE (G4 * 640)
#define N_WT (G4 * 576)
#define N_W1 (256 * 512)
#define N_E2 (64 * 512)
__global__ void pack_all(
    u16* __restrict__ Weh, u16* __restrict__ Wel,
    u16* __restrict__ Wth, u16* __restrict__ Wtl, float* __restrict__ Wt576,
    u16* __restrict__ W1h,
    u16* __restrict__ E2h, u16* __restrict__ E2l,
    float* __restrict__ be, float* __restrict__ ba, float* __restrict__ bt,
    const float* __restrict__ eWih, const float* __restrict__ eWhh,
    const float* __restrict__ tWih, const float* __restrict__ tWhh,
    const float* __restrict__ ts1W, const float* __restrict__ e2W,
    const float* __restrict__ ebih, const float* __restrict__ ebhh,
    const float* __restrict__ abih, const float* __restrict__ abhh,
    const float* __restrict__ tbih, const float* __restrict__ tbhh)
{
    int idx = blockIdx.x * 256 + threadIdx.x;
    if (idx < N_WE) {
        int np = idx / 640, k = idx - np * 640;
        int n = perm_src(np);
        float v = 0.f;
        if (k < 65) v = eWih[n * 65 + k];
        else if (k < 577) v = eWhh[(n << 9) + k - 65];
        u16 h = f2bf(v); Weh[idx] = h; Wel[idx] = f2bf(v - bf2f(h));
        return;
    }
    idx -= N_WE;
    if (idx < N_WT) {
        int np = idx / 576, k = idx - np * 576;
        int n = perm_src(np);
        float v = (k < 512) ? tWhh[(n << 9) + k] : tWih[n * 585 + 520 + (k - 512)];
        u16 h = f2bf(v); Wth[idx] = h; Wtl[idx] = f2bf(v - bf2f(h));
        return;
    }
    idx -= N_WT;
    if (idx < N_W1) { W1h[idx] = f2bf(ts1W[idx]); return; }
    idx -= N_W1;
    if (idx < N_E2) {
        float v = e2W[idx];
        u16 h = f2bf(v); E2h[idx] = h; E2l[idx] = f2bf(v - bf2f(h));
        return;
    }
    idx -= N_E2;
    if (idx < G4) {
        int n = perm_src(idx);
        be[idx] = ebih[n] + ebhh[n];
        ba[idx] = abih[n] + abhh[n];
        bt[idx] = tbih[n] + tbhh[n];
        Wt576[idx] = tWih[n * 585 + 584];
    }
}

__global__ void pack_wa(u16* __restrict__ hi, u16* __restrict__ lo,
                        const float* __restrict__ wih, const float* __restrict__ whh) {
    int idx = blockIdx.x * 256 + threadIdx.x;
    if (idx >= G4 * 576) return;
    int np = idx / 576, k = idx - np * 576;
    int n = perm_src(np);
    float v = (k < 64) ? wih[n * 584 + 520 + k] : whh[(n << 9) + k - 64];
    u16 h = f2bf(v); hi[idx] = h; lo[idx] = f2bf(v - bf2f(h));
}

// ---------------------------------------------------------------------------
// init: packed X buffers (Xe stride 640), c states, lens, tcat attr, tsP,
// barrier counters (cnts[0] encoder, cnts[64] decoder — inside 512B alloc).
// ---------------------------------------------------------------------------
__global__ __launch_bounds__(256) void init_all(
    u32* __restrict__ Xe, float* __restrict__ c_e, int* __restrict__ lens,
    float* __restrict__ tcat,
    u32* __restrict__ Xa, u32* __restrict__ Xt,
    float* __restrict__ c_a, float* __restrict__ c_t,
    float* __restrict__ tsP, unsigned* __restrict__ cnts,
    const int* __restrict__ acts, const float* __restrict__ tsv,
    const float* __restrict__ act_emb,
    const int* __restrict__ attr_cat, const float* __restrict__ attr_num,
    const float* __restrict__ attr_emb,
    const float* __restrict__ a2aW, const float* __restrict__ a2ab)
{
    int b = blockIdx.x, tid = threadIdx.x;
    for (int j = tid; j < 640; j += 256) {
        float v = 0.f;
        if (j < 64) v = act_emb[acts[b << 6] * 64 + j];
        else if (j == 64) v = tsv[b << 6];
        Xe[b * 640 + j] = packbf(v);
        if (j >= 577) Xe[512 * 640 + b * 640 + j] = 0u;
    }
    for (int j = tid; j < CF; j += 256) {
        c_e[(b << 9) + j] = 0.f; c_a[(b << 9) + j] = 0.f; c_t[(b << 9) + j] = 0.f;
        Xt[(b << 9) + j] = 0u;
    }
    for (int j = tid; j < 576; j += 256)
        Xa[b * 576 + j] = packbf((j < 64) ? act_emb[63 * 64 + j] : 0.f);
    if (tid < 64) {
        int v = acts[(b << 6) + tid];
        int m = v;
        #pragma unroll
        for (int off = 32; off; off >>= 1) m = max(m, __shfl_xor(m, off));
        unsigned long long mask = __ballot(v == m);
        if (tid == 0) lens[b] = __ffsll(mask) - 1;
    }
    if (tid < 8) {
        const float* wr = a2aW + tid * 17;
        const float* em = attr_emb + attr_cat[b] * 16;
        float s = a2ab[tid];
        #pragma unroll
        for (int k = 0; k < 16; ++k) s = fmaf(em[k], wr[k], s);
        s = fmaf(attr_num[b], wr[16], s);
        tcat[b * TDIM + tid] = fmaxf(s, 0.f);
    }
    if (b < 2) {
        for (int j = tid; j < 512; j += 256) tsP[(b << 9) + j] = 0.f;
        if (tid == 0) cnts[b * 64] = 0u;   // cnts[0]=encoder, cnts[64]=decoder
    }
}

__global__ __launch_bounds__(64) void attr_heads(
    const float* __restrict__ hid1, const float* __restrict__ hid2,
    const float* __restrict__ tc2W, const float* __restrict__ tc2b,
    const float* __restrict__ tn2W, const float* __restrict__ tn2b,
    float* __restrict__ out_cat, float* __restrict__ out_num) {
    __shared__ __align__(16) float h1[260], h2[260], sl[10];
    int b = blockIdx.x, tid = threadIdx.x;
    for (int k = tid; k < 260; k += 64) {
        h1[k] = hid1[b * 260 + k];
        h2[k] = hid2[b * 260 + k];
    }
    __syncthreads();
    if (tid < 10) {
        float l = tc2b[tid];
        const float* wr = tc2W + tid * 260;
        for (int k = 0; k < 260; ++k) l = fmaf(h1[k], wr[k], l);
        sl[tid] = l;
    }
    __syncthreads();
    if (tid < 10) {
        float m = sl[0];
        for (int i = 1; i < 10; ++i) m = fmaxf(m, sl[i]);
        float ssum = 0.f;
        for (int i = 0; i < 10; ++i) ssum += expf(sl[i] - m);
        out_cat[b * 10 + tid] = expf(sl[tid] - m) / ssum;
    }
    float p = 0.f;
    for (int k = tid; k < 260; k += 64) p = fmaf(h2[k], tn2W[k], p);
    #pragma unroll
    for (int off = 32; off; off >>= 1) p += __shfl_xor(p, off);
    if (tid == 0) out_num[b] = 1.f / (1.f + expf(-(p + tn2b[0])));
}

// ---------------------------------------------------------------------------
extern "C" void kernel_launch(void* const* d_in, const int* in_sizes, int n_in,
                              void* d_out, int out_size, void* d_ws, size_t ws_size,
                              hipStream_t stream) {
    const int*   attr_cat = (const int*)  d_in[0];
    const float* attr_num = (const float*)d_in[1];
    const int*   acts     = (const int*)  d_in[2];
    const float* tsv      = (const float*)d_in[3];
    const float* eps      = (const float*)d_in[4];
    const float* attr_emb = (const float*)d_in[5];
    const float* a2a_W    = (const float*)d_in[6];
    const float* a2a_b    = (const float*)d_in[7];
    const float* act_emb  = (const float*)d_in[8];
    const float* eWih     = (const float*)d_in[9];
    const float* eWhh     = (const float*)d_in[10];
    const float* ebih     = (const float*)d_in[11];
    const float* ebhh     = (const float*)d_in[12];
    const float* mean_W   = (const float*)d_in[13];
    const float* mean_b   = (const float*)d_in[14];
    const float* var_W    = (const float*)d_in[15];
    const float* var_b    = (const float*)d_in[16];
    const float* z2t_W    = (const float*)d_in[17];
    const float* z2t_b    = (const float*)d_in[18];
    const float* tc1_W    = (const float*)d_in[19];
    const float* tc1_b    = (const float*)d_in[20];
    const float* tc2_W    = (const float*)d_in[21];
    const float* tc2_b    = (const float*)d_in[22];
    const float* tn1_W    = (const float*)d_in[23];
    const float* tn1_b    = (const float*)d_in[24];
    const float* tn2_W    = (const float*)d_in[25];
    const float* tn2_b    = (const float*)d_in[26];
    const float* aWih     = (const float*)d_in[27];
    const float* aWhh     = (const float*)d_in[28];
    const float* abih     = (const float*)d_in[29];
    const float* abhh     = (const float*)d_in[30];
    const float* tWih     = (const float*)d_in[31];
    const float* tWhh     = (const float*)d_in[32];
    const float* tbih     = (const float*)d_in[33];
    const float* tbhh     = (const float*)d_in[34];
    const float* e2act_W  = (const float*)d_in[35];
    const float* e2act_b  = (const float*)d_in[36];
    const float* ts1_W    = (const float*)d_in[37];
    const float* ts1_b    = (const float*)d_in[38];
    const float* ts2_W    = (const float*)d_in[39];
    const float* ts2_b    = (const float*)d_in[40];

    float* out = (float*)d_out;
    float* out_cat  = out;
    float* out_num  = out + 5120;
    float* out_acts = out + 5632;
    float* out_ts   = out + 2102784;
    float* outm     = out + 2135552;
    float* outv     = out + 2201088;

    char* w = (char*)d_ws;
    auto alloc = [&](size_t bytes) { char* p = w; w += (bytes + 255) & ~(size_t)255; return p; };
    // --- persistent region ---
    u16*   Wt_hi  = (u16*)alloc((size_t)G4 * 576 * 2);
    u16*   Wt_lo  = (u16*)alloc((size_t)G4 * 576 * 2);
    float* Wt576  = (float*)alloc(G4 * 4);
    u16*   W1h    = (u16*)alloc(256 * 512 * 2);
    u16*   E2h    = (u16*)alloc(64 * 512 * 2);
    u16*   E2l    = (u16*)alloc(64 * 512 * 2);
    float* bias_e = (float*)alloc(G4 * 4);
    float* bias_a = (float*)alloc(G4 * 4);
    float* bias_t = (float*)alloc(G4 * 4);
    float* base_a = (float*)alloc((size_t)B * G4 * 4);
    float* base_t = (float*)alloc((size_t)B * G4 * 4);
    u32*   Xa     = (u32*)alloc((size_t)2 * B * 576 * 4);
    u32*   Xt     = (u32*)alloc((size_t)2 * B * 512 * 4);
    float* c_a    = (float*)alloc((size_t)B * CF * 4);
    float* c_t    = (float*)alloc((size_t)B * CF * 4);
    float* tcat   = (float*)alloc((size_t)B * TDIM * 4);
    float* t_rec  = (float*)alloc((size_t)B * TDIM * 4);
    float* hid1   = (float*)alloc((size_t)B * 260 * 4);
    float* hid2   = (float*)alloc((size_t)B * 260 * 4);
    int*   lens   = (int*)alloc(512 * 4);
    float* tsP    = (float*)alloc(2 * 512 * 4);
    unsigned* cnts = (unsigned*)alloc(512);   // [0]=enc ctr, [64]=dec ctr
    // --- phase overlay: encoder {We, Xe, c_e} / decoder {Wa} ---
    char* phase = w;
    u16*   We_hi  = (u16*)(phase);
    u16*   We_lo  = (u16*)(phase + (size_t)G4 * 640 * 2);
    u32*   Xe     = (u32*)(phase + (size_t)2 * G4 * 640 * 2);
    float* c_e    = (float*)(phase + (size_t)2 * G4 * 640 * 2 + (size_t)2 * B * 640 * 4);
    u16*   Wa_hi  = (u16*)(phase);
    u16*   Wa_lo  = (u16*)(phase + (size_t)G4 * 576 * 2);
    (void)ws_size; (void)in_sizes; (void)n_in; (void)out_size;

    // ---- prep ----
    {
        int total = N_WE + N_WT + N_W1 + N_E2 + G4;
        pack_all<<<(total + 255) / 256, 256, 0, stream>>>(
            We_hi, We_lo, Wt_hi, Wt_lo, Wt576, W1h, E2h, E2l,
            bias_e, bias_a, bias_t,
            eWih, eWhh, tWih, tWhh, ts1_W, e2act_W,
            ebih, ebhh, abih, abhh, tbih, tbhh);
    }
    init_all<<<B, 256, 0, stream>>>(
        Xe, c_e, lens, tcat, Xa, Xt, c_a, c_t, tsP, cnts,
        acts, tsv, act_emb, attr_cat, attr_num, attr_emb, a2a_W, a2a_b);

    // ---- encoder (1 persistent cooperative launch, 512 threads/block) ----
    EncArgs ea;
    ea.Xe = Xe; ea.Weh = We_hi; ea.Wel = We_lo; ea.bias_e = bias_e;
    ea.c_e = c_e; ea.tcat = tcat; ea.lens = lens;
    ea.acts = acts; ea.tsv = tsv; ea.act_emb = act_emb; ea.cnt = cnts;
    {
        void* args[] = { &ea };
        hipLaunchCooperativeKernel((const void*)enc_persist, dim3(256), dim3(512),
                                   args, 0, stream);
    }

    // ---- decoder weight pack (overlays We after encoder) ----
    pack_wa<<<(G4 * 576 + 255) / 256, 256, 0, stream>>>(Wa_hi, Wa_lo, aWih, aWhh);

    // ---- latent ----
    gemm_tn<<<dim3(2, 8, 2), 256, 0, stream>>>(
        tcat, nullptr, nullptr, nullptr, TDIM, mean_W, TDIM, var_W, TDIM,
        ZD, TDIM, mean_b, var_b, outm, outv, ZD, 0, 0);
    gemm_tn<<<dim3(9, 8, 1), 256, 0, stream>>>(
        nullptr, outm, outv, eps, ZD, z2t_W, ZD, nullptr, 0,
        TDIM, ZD, z2t_b, nullptr, t_rec, nullptr, TDIM, 1, 0);
    gemm_tn<<<dim3(5, 8, 2), 256, 0, stream>>>(
        t_rec, nullptr, nullptr, nullptr, TDIM, tc1_W, TDIM, tn1_W, TDIM,
        260, TDIM, tc1_b, tn1_b, hid1, hid2, 260, 1, 0);
    attr_heads<<<B, 64, 0, stream>>>(hid1, hid2, tc2_W, tc2_b, tn2_W, tn2_b, out_cat, out_num);
    gemm_tn<<<dim3(32, 8, 2), 256, 0, stream>>>(
        t_rec, nullptr, nullptr, nullptr, TDIM, aWih, 584, tWih, 585,
        G4, TDIM, bias_a, bias_t, base_a, base_t, G4, 0, 1);

    // ---- decoder (1 persistent cooperative launch, 512 threads/block) ----
    DecArgs da;
    da.Xa = Xa; da.Xt = Xt;
    da.Wah = Wa_hi; da.Wal = Wa_lo; da.Wth = Wt_hi; da.Wtl = Wt_lo; da.Wt576 = Wt576;
    da.base_a = base_a; da.base_t = base_t;
    da.c_a = c_a; da.c_t = c_t;
    da.E2h = E2h; da.E2l = E2l; da.e2b = e2act_b; da.act_emb = act_emb;
    da.out_acts = out_acts; da.out_ts = out_ts;
    da.W1h = W1h; da.b1 = ts1_b; da.w2 = ts2_W; da.b2 = ts2_b;
    da.tsP = tsP; da.cnt = cnts + 64;
    {
        void* args[] = { &da };
        hipLaunchCooperativeKernel((const void*)dec_persist, dim3(256), dim3(512),
                                   args, 0, stream);
    }
}